// Round 9
// baseline (402.126 us; speedup 1.0000x reference)
//
#include <hip/hip_runtime.h>
#include <hip/hip_bf16.h>

#define NUM_REAL 19
#define NIMG     4
#define T_TOT    76        // NIMG*NUM_REAL
#define V_SEL    131       // 10000 / 76
#define M_ROWS   9956      // T_TOT*V_SEL
#define MP       9984      // padded to 78*128
#define CDIM     256
#define P_PIX    65536
#define TILE     128
#define BK       32
#define RPI      2489      // rows per image = 19*131
#define NT1      3081      // 78*79/2 upper-triangular tiles
#define NCHUNK   32        // label chunks per image
#define CHPIX    2048      // dom pixels per chunk
#define CT       5         // 128-row tiles per 524-row class block
#define NT2      (NUM_REAL * 15)   // 19 classes * C(5+1,2) upper tiles

typedef __attribute__((ext_vector_type(8))) short short8;
typedef __attribute__((ext_vector_type(4))) float floatx4;

__device__ __forceinline__ void gld_lds16(const unsigned short* g, unsigned short* l) {
    // direct global->LDS, 16B per lane; LDS dest = wave-uniform base + lane*16
    __builtin_amdgcn_global_load_lds((__attribute__((address_space(1))) void*)(g),
                                     (__attribute__((address_space(3))) void*)(l),
                                     16, 0, 0);
}

// ---------------- Kernel 1a: per-chunk class histograms + workspace zeroing ----------------
__global__ __launch_bounds__(256) void k_hist(const int* __restrict__ label,
                                              int* __restrict__ ghist,
                                              float* __restrict__ negsum,
                                              float* __restrict__ out)
{
    __shared__ int h[NUM_REAL];
    const int img = blockIdx.y, ch = blockIdx.x, tid = threadIdx.x;
    if (img == 0) {                       // fold the two memset dispatches in here
        #pragma unroll
        for (int i = 0; i < (MP / NCHUNK); i += 256)
            if (i + tid < (MP / NCHUNK))
                negsum[ch * (MP / NCHUNK) + i + tid] = 0.f;
        if (ch == 0 && tid == 0) out[0] = 0.f;
    }
    if (tid < NUM_REAL) h[tid] = 0;
    __syncthreads();
    const int* lab = label + img * 1048576;
    const int p0 = ch * CHPIX + tid * 8;
    #pragma unroll
    for (int j = 0; j < 8; ++j) {
        int p = p0 + j;
        int c = lab[((p >> 8) << 12) + ((p & 255) << 2)];
        atomicAdd(&h[c], 1);
    }
    __syncthreads();
    if (tid < NUM_REAL) ghist[(img * NCHUNK + ch) * NUM_REAL + tid] = h[tid];
}

// ---------------- Kernel 1b: ordered scatter of first-131 pixels per class ----------------
__global__ __launch_bounds__(256) void k_scatter(const int* __restrict__ label,
                                                 const int* __restrict__ ghist,
                                                 int* __restrict__ sel)
{
    __shared__ int cnt[NUM_REAL * 256];
    __shared__ int base[NUM_REAL];
    const int img = blockIdx.y, ch = blockIdx.x, tid = threadIdx.x;
    #pragma unroll
    for (int k = 0; k < NUM_REAL; ++k) cnt[k * 256 + tid] = 0;   // own slots only
    if (tid < NUM_REAL) {
        int b = 0;
        for (int q = 0; q < ch; ++q) b += ghist[(img * NCHUNK + q) * NUM_REAL + tid];
        base[tid] = b;
    }
    const int* lab = label + img * 1048576;
    const int p0 = ch * CHPIX + tid * 8;
    #pragma unroll
    for (int j = 0; j < 8; ++j) {
        int p = p0 + j;
        int c = lab[((p >> 8) << 12) + ((p & 255) << 2)];
        cnt[c * 256 + tid]++;
    }
    __syncthreads();
    // wave-parallel exclusive scan: wave w owns classes w, w+4, ... (exact integer
    // equivalence with the old 1-thread-per-class serial scan)
    const int wave = tid >> 6, lane = tid & 63;
    for (int k = wave; k < NUM_REAL; k += 4) {
        const int bb = k * 256;
        int x0 = cnt[bb + lane],       x1 = cnt[bb + 64 + lane],
            x2 = cnt[bb + 128 + lane], x3 = cnt[bb + 192 + lane];
        const int v0 = x0, v1 = x1, v2 = x2, v3 = x3;
        #pragma unroll
        for (int d = 1; d < 64; d <<= 1) {
            int t0 = __shfl_up(x0, d, 64), t1 = __shfl_up(x1, d, 64);
            int t2 = __shfl_up(x2, d, 64), t3 = __shfl_up(x3, d, 64);
            if (lane >= d) { x0 += t0; x1 += t1; x2 += t2; x3 += t3; }
        }
        const int s0 = __shfl(x0, 63, 64);
        const int s1 = __shfl(x1, 63, 64);
        const int s2 = __shfl(x2, 63, 64);
        const int b0 = base[k];
        cnt[bb + lane]       = b0 + x0 - v0;
        cnt[bb + 64 + lane]  = b0 + s0 + x1 - v1;
        cnt[bb + 128 + lane] = b0 + s0 + s1 + x2 - v2;
        cnt[bb + 192 + lane] = b0 + s0 + s1 + s2 + x3 - v3;
    }
    __syncthreads();
    bool need = false;
    #pragma unroll
    for (int k = 0; k < NUM_REAL; ++k) if (cnt[k * 256 + tid] < V_SEL) need = true;
    if (need) {
        for (int j = 0; j < 8; ++j) {
            int p = p0 + j;
            int c = lab[((p >> 8) << 12) + ((p & 255) << 2)];
            int r = cnt[c * 256 + tid]++;
            if (r < V_SEL) sel[(img * NUM_REAL + c) * V_SEL + r] = p;
        }
    }
}

// ---------------- Kernel 2: fused gather + L2-normalize -> bf16 F[MP][256] ----------------
// one wave per output row: gather 256 channels, butterfly-reduce the norm,
// bf16 convert, in-wave LDS transpose, one ushort4 store per lane.
__global__ __launch_bounds__(256) void k_gather(const float* __restrict__ feats,
                                                const int* __restrict__ sel,
                                                unsigned short* __restrict__ F)
{
    __shared__ unsigned short rowbuf[4][256];
    const int tid = threadIdx.x, wave = tid >> 6, lane = tid & 63;
    const int r = blockIdx.x * 4 + wave;
    if (r < M_ROWS) {
        const int b = r / RPI;
        const int p = sel[r];
        const float* f0 = feats + (size_t)b * CDIM * P_PIX + p;
        float x0 = f0[(size_t)(lane      ) * P_PIX];
        float x1 = f0[(size_t)(lane + 64 ) * P_PIX];
        float x2 = f0[(size_t)(lane + 128) * P_PIX];
        float x3 = f0[(size_t)(lane + 192) * P_PIX];
        float ss = x0 * x0 + x1 * x1 + x2 * x2 + x3 * x3;
        #pragma unroll
        for (int d = 1; d < 64; d <<= 1) ss += __shfl_xor(ss, d, 64);
        const float rinv = 1.0f / fmaxf(sqrtf(ss), 1e-12f);
        __hip_bfloat16 h0 = __float2bfloat16(x0 * rinv);
        __hip_bfloat16 h1 = __float2bfloat16(x1 * rinv);
        __hip_bfloat16 h2 = __float2bfloat16(x2 * rinv);
        __hip_bfloat16 h3 = __float2bfloat16(x3 * rinv);
        rowbuf[wave][lane      ] = *reinterpret_cast<unsigned short*>(&h0);
        rowbuf[wave][lane + 64 ] = *reinterpret_cast<unsigned short*>(&h1);
        rowbuf[wave][lane + 128] = *reinterpret_cast<unsigned short*>(&h2);
        rowbuf[wave][lane + 192] = *reinterpret_cast<unsigned short*>(&h3);
        // same-wave LDS RAW: compiler inserts lgkmcnt wait; lanes are lockstep, no barrier
        ushort4 o = *reinterpret_cast<ushort4*>(&rowbuf[wave][lane * 4]);
        *reinterpret_cast<ushort4*>(F + (size_t)r * CDIM + lane * 4) = o;
    } else if (r < MP) {
        ushort4 z; z.x = z.y = z.z = z.w = 0;
        *reinterpret_cast<ushort4*>(F + (size_t)r * CDIM + lane * 4) = z;
    }
}

// ---------------- Kernel 3: symmetric Gram, fused different-class exp sums -> negsum ----------------
// T2 LDS chunk swizzle, full spread: physical 16B chunk (r,c) holds logical chunk
// c ^ f(r), f(r) = (r&3) ^ ((r>>2)&1). Staging pre-swizzles the GLOBAL source column
// (LDS dest stays linear, rule #21); reads use chunk qr^f(row). Per 16-lane read
// phase: 8 bank-slots x 2 lanes = the free 2-way aliasing floor.
__global__ __launch_bounds__(256) void k_gemm(const unsigned short* __restrict__ F,
                                              float* __restrict__ negsum)
{
    __shared__ unsigned short As[2][TILE * BK];
    __shared__ unsigned short Bs[2][TILE * BK];

    int t = blockIdx.x;                      // upper-triangular tile decode
    int bi = (int)((157.0f - sqrtf(24649.0f - 8.0f * (float)t)) * 0.5f);
    if (bi < 0) bi = 0;
    if (bi > 77) bi = 77;
    while ((bi + 1) * 78 - ((bi + 1) * bi) / 2 <= t) ++bi;
    while (bi * 78 - (bi * (bi - 1)) / 2 > t) --bi;
    int bj = bi + (t - (bi * 78 - (bi * (bi - 1)) / 2));
    const bool diag = (bi == bj);
    const int i0 = bi * TILE, j0 = bj * TILE;

    const int tid  = threadIdx.x;
    const int wave = tid >> 6, lane = tid & 63;
    const int qr = lane >> 4, lr = lane & 15;
    const int wr = (wave >> 1) * 64, wc = (wave & 1) * 64;

    floatx4 acc[4][4];
    floatx4 zero4 = {0.f, 0.f, 0.f, 0.f};
    #pragma unroll
    for (int a = 0; a < 4; ++a)
        #pragma unroll
        for (int b = 0; b < 4; ++b) acc[a][b] = zero4;

    const int srow = wave * 32 + (lane >> 2);
    // source logical chunk = (lane&3) ^ f(srow), f(srow) = ((lane>>2)&3) ^ ((lane>>4)&1)
    const int scol = ((lane & 3) ^ ((lane >> 2) & 3) ^ ((lane >> 4) & 1)) * 8;
    const unsigned short* gA = F + (size_t)(i0 + srow) * CDIM + scol;
    const unsigned short* gB = F + (size_t)(j0 + srow) * CDIM + scol;
    const int l0 = (wave * 32) * BK, l1 = (wave * 32 + 16) * BK;

    gld_lds16(gA,             &As[0][l0]);
    gld_lds16(gA + 16 * CDIM, &As[0][l1]);
    gld_lds16(gB,             &Bs[0][l0]);
    gld_lds16(gB + 16 * CDIM, &Bs[0][l1]);

    const int rchunk = (qr ^ (lr & 3) ^ ((lr >> 2) & 1)) * 8;  // swizzled read chunk

    #pragma unroll 2
    for (int k = 0; k < 8; ++k) {
        __syncthreads();                      // staging of buf[k&1] now visible
        const int cur = k & 1, nxt = cur ^ 1;
        if (k < 7) {                          // prefetch next chunk; drains at NEXT barrier
            const int kc = (k + 1) * BK;
            gld_lds16(gA + kc,             &As[nxt][l0]);
            gld_lds16(gA + kc + 16 * CDIM, &As[nxt][l1]);
            gld_lds16(gB + kc,             &Bs[nxt][l0]);
            gld_lds16(gB + kc + 16 * CDIM, &Bs[nxt][l1]);
        }
        short8 a[4], b[4];
        #pragma unroll
        for (int mi = 0; mi < 4; ++mi)
            a[mi] = *reinterpret_cast<const short8*>(&As[cur][(wr + mi * 16 + lr) * BK + rchunk]);
        #pragma unroll
        for (int ni = 0; ni < 4; ++ni)
            b[ni] = *reinterpret_cast<const short8*>(&Bs[cur][(wc + ni * 16 + lr) * BK + rchunk]);
        #pragma unroll
        for (int mi = 0; mi < 4; ++mi)
            #pragma unroll
            for (int ni = 0; ni < 4; ++ni)
                acc[mi][ni] = __builtin_amdgcn_mfma_f32_16x16x32_bf16(a[mi], b[ni], acc[mi][ni], 0, 0, 0);
    }

    // ---- epilogue: ns partial sums (different-class exp), LDS-staged, 256 atomics/tile ----
    int jcls[4];
    bool jval[4];
    #pragma unroll
    for (int ni = 0; ni < 4; ++ni) {
        int gcol = j0 + wc + ni * 16 + lr;
        jval[ni] = gcol < M_ROWS;
        unsigned tj = (unsigned)gcol / V_SEL;
        jcls[ni] = (int)(tj - (tj / NUM_REAL) * NUM_REAL);
    }
    float* red  = (float*)&As[0][0];   // [128][2] row partials (col-half per slot)
    float* cred = (float*)&Bs[0][0];   // [128][2] col partials (row-half per slot)
    float colacc[4] = {0.f, 0.f, 0.f, 0.f};
    #pragma unroll
    for (int mi = 0; mi < 4; ++mi) {
        #pragma unroll
        for (int reg = 0; reg < 4; ++reg) {
            int rloc = wr + mi * 16 + qr * 4 + reg;
            int grow = i0 + rloc;
            bool ival = grow < M_ROWS;
            unsigned ti = (unsigned)grow / V_SEL;
            int icls = (int)(ti - (ti / NUM_REAL) * NUM_REAL);
            float rowacc = 0.f;
            #pragma unroll
            for (int ni = 0; ni < 4; ++ni) {
                bool v = ival && jval[ni] && (icls != jcls[ni]);
                float e = v ? __expf(acc[mi][ni][reg] * 2.0f) : 0.f;
                rowacc += e;
                colacc[ni] += e;
            }
            rowacc += __shfl_xor(rowacc, 1, 64);
            rowacc += __shfl_xor(rowacc, 2, 64);
            rowacc += __shfl_xor(rowacc, 4, 64);
            rowacc += __shfl_xor(rowacc, 8, 64);
            if (lr == 0) red[rloc * 2 + (wave & 1)] = rowacc;
        }
    }
    #pragma unroll
    for (int ni = 0; ni < 4; ++ni) {
        float cc = colacc[ni];
        cc += __shfl_xor(cc, 16, 64);
        cc += __shfl_xor(cc, 32, 64);
        if (qr == 0) cred[(wc + ni * 16 + lr) * 2 + (wave >> 1)] = cc;
    }
    __syncthreads();
    if (tid < 128) {
        int row = i0 + tid;
        if (row < M_ROWS) atomicAdd(&negsum[row], red[tid * 2] + red[tid * 2 + 1]);
    } else {
        int cc2 = tid - 128, col = j0 + cc2;
        if (!diag && col < M_ROWS) atomicAdd(&negsum[col], cred[cc2 * 2] + cred[cc2 * 2 + 1]);
    }
}

// ---------------- Kernel 4: same-class Gram tiles -> positive loss terms ----------------
__global__ __launch_bounds__(256) void k_pos(const unsigned short* __restrict__ F,
                                             const float* __restrict__ negsum,
                                             float* __restrict__ out)
{
    __shared__ unsigned short As[2][TILE * BK];
    __shared__ unsigned short Bs[2][TILE * BK];
    __shared__ float wred[4];

    const int c = blockIdx.x / 15;
    int pidx = blockIdx.x % 15;
    int ti = 0;
    while (pidx >= CT - ti) { pidx -= CT - ti; ++ti; }
    const int tj = ti + pidx;
    const int u0i = ti * TILE, u0j = tj * TILE;
    const bool offd = (ti != tj);

    const int tid  = threadIdx.x;
    const int wave = tid >> 6, lane = tid & 63;
    const int qr = lane >> 4, lr = lane & 15;
    const int wr = (wave >> 1) * 64, wc = (wave & 1) * 64;

    floatx4 acc[4][4];
    floatx4 zero4 = {0.f, 0.f, 0.f, 0.f};
    #pragma unroll
    for (int a = 0; a < 4; ++a)
        #pragma unroll
        for (int b = 0; b < 4; ++b) acc[a][b] = zero4;

    const int srow = wave * 32 + (lane >> 2);
    const int scol = ((lane & 3) ^ ((lane >> 2) & 3) ^ ((lane >> 4) & 1)) * 8;
    auto growmap = [&](int u) -> int {
        int uc = u < 524 ? u : 523;
        int b = uc / 131, v = uc - 131 * b;
        return b * RPI + c * V_SEL + v;
    };
    const unsigned short* gA0 = F + (size_t)growmap(u0i + srow) * CDIM + scol;
    const unsigned short* gA1 = F + (size_t)growmap(u0i + srow + 16) * CDIM + scol;
    const unsigned short* gB0 = F + (size_t)growmap(u0j + srow) * CDIM + scol;
    const unsigned short* gB1 = F + (size_t)growmap(u0j + srow + 16) * CDIM + scol;
    const int l0 = (wave * 32) * BK, l1 = (wave * 32 + 16) * BK;

    gld_lds16(gA0, &As[0][l0]);
    gld_lds16(gA1, &As[0][l1]);
    gld_lds16(gB0, &Bs[0][l0]);
    gld_lds16(gB1, &Bs[0][l1]);

    const int rchunk = (qr ^ (lr & 3) ^ ((lr >> 2) & 1)) * 8;  // swizzled read chunk

    #pragma unroll 2
    for (int k = 0; k < 8; ++k) {
        __syncthreads();
        const int cur = k & 1, nxt = cur ^ 1;
        if (k < 7) {
            const int kc = (k + 1) * BK;
            gld_lds16(gA0 + kc, &As[nxt][l0]);
            gld_lds16(gA1 + kc, &As[nxt][l1]);
            gld_lds16(gB0 + kc, &Bs[nxt][l0]);
            gld_lds16(gB1 + kc, &Bs[nxt][l1]);
        }
        short8 a[4], b[4];
        #pragma unroll
        for (int mi = 0; mi < 4; ++mi)
            a[mi] = *reinterpret_cast<const short8*>(&As[cur][(wr + mi * 16 + lr) * BK + rchunk]);
        #pragma unroll
        for (int ni = 0; ni < 4; ++ni)
            b[ni] = *reinterpret_cast<const short8*>(&Bs[cur][(wc + ni * 16 + lr) * BK + rchunk]);
        #pragma unroll
        for (int mi = 0; mi < 4; ++mi)
            #pragma unroll
            for (int ni = 0; ni < 4; ++ni)
                acc[mi][ni] = __builtin_amdgcn_mfma_f32_16x16x32_bf16(a[mi], b[ni], acc[mi][ni], 0, 0, 0);
    }

    int  ujv[4];
    bool jval[4];
    float nsj[4];
    #pragma unroll
    for (int ni = 0; ni < 4; ++ni) {
        int uj = u0j + wc + ni * 16 + lr;
        ujv[ni] = uj;
        jval[ni] = uj < 524;
        nsj[ni] = jval[ni] ? negsum[growmap(uj)] : 0.f;
    }
    float tsum = 0.f;
    #pragma unroll
    for (int mi = 0; mi < 4; ++mi) {
        #pragma unroll
        for (int reg = 0; reg < 4; ++reg) {
            int ui = u0i + wr + mi * 16 + qr * 4 + reg;
            bool ival = ui < 524;
            float nsi = ival ? negsum[growmap(ui)] : 0.f;
            #pragma unroll
            for (int ni = 0; ni < 4; ++ni) {
                if (ival && jval[ni] && ui != ujv[ni]) {
                    float l  = acc[mi][ni][reg] * 2.0f;
                    float el = __expf(l);
                    tsum += l - __logf(el + nsi);
                    if (offd) tsum += l - __logf(el + nsj[ni]);
                }
            }
        }
    }
    #pragma unroll
    for (int s = 32; s > 0; s >>= 1) tsum += __shfl_xor(tsum, s, 64);
    if (lane == 0) wred[wave] = tsum;
    __syncthreads();
    if (tid == 0) {
        const float scale = -1.0f / (523.0f * (float)M_ROWS);
        atomicAdd(out, (wred[0] + wred[1] + wred[2] + wred[3]) * scale);
    }
}

extern "C" void kernel_launch(void* const* d_in, const int* in_sizes, int n_in,
                              void* d_out, int out_size, void* d_ws, size_t ws_size,
                              hipStream_t stream)
{
    const int*   label = (const int*)d_in[0];
    const float* feats = (const float*)d_in[1];
    float*       out   = (float*)d_out;

    char* ws = (char*)d_ws;
    unsigned short* F = (unsigned short*)ws;                    // MP*CDIM*2 = 5,111,808 B
    size_t off = (size_t)MP * CDIM * 2;
    int* sel = (int*)(ws + off);
    off += (size_t)T_TOT * V_SEL * 4;
    off = (off + 255) & ~(size_t)255;
    float* negsum = (float*)(ws + off);                         // MP floats
    off += (size_t)MP * 4;
    int* ghist = (int*)(ws + off);                              // 4*32*19 ints
    off += (size_t)NIMG * NCHUNK * NUM_REAL * 4;

    dim3 gh(NCHUNK, NIMG);
    k_hist<<<gh, 256, 0, stream>>>(label, ghist, negsum, out);
    k_scatter<<<gh, 256, 0, stream>>>(label, ghist, sel);
    k_gather<<<MP / 4, 256, 0, stream>>>(feats, sel, F);
    k_gemm<<<NT1, 256, 0, stream>>>(F, negsum);
    k_pos<<<NT2, 256, 0, stream>>>(F, negsum, out);
}

// Round 10
// 400.666 us; speedup vs baseline: 1.0036x; 1.0036x over previous
//
#include <hip/hip_runtime.h>
#include <hip/hip_bf16.h>

#define NUM_REAL 19
#define NIMG     4
#define T_TOT    76        // NIMG*NUM_REAL
#define V_SEL    131       // 10000 / 76
#define M_ROWS   9956      // T_TOT*V_SEL
#define MP       9984      // padded to 78*128
#define CDIM     256
#define P_PIX    65536
#define TILE     128
#define BK       32
#define RPI      2489      // rows per image = 19*131
#define NT1      3081      // 78*79/2 upper-triangular tiles
#define NCHUNK   32        // label chunks per image
#define CHPIX    2048      // dom pixels per chunk
#define CT       5         // 128-row tiles per 524-row class block
#define NT2      (NUM_REAL * 15)   // 19 classes * C(5+1,2) upper tiles

typedef __attribute__((ext_vector_type(8))) short short8;
typedef __attribute__((ext_vector_type(4))) float floatx4;

__device__ __forceinline__ void gld_lds16(const unsigned short* g, unsigned short* l) {
    // direct global->LDS, 16B per lane; LDS dest = wave-uniform base + lane*16
    __builtin_amdgcn_global_load_lds((__attribute__((address_space(1))) void*)(g),
                                     (__attribute__((address_space(3))) void*)(l),
                                     16, 0, 0);
}

// ---------------- Kernel 1a: per-chunk class histograms + workspace zeroing ----------------
__global__ __launch_bounds__(256) void k_hist(const int* __restrict__ label,
                                              int* __restrict__ ghist,
                                              float* __restrict__ negsum,
                                              float* __restrict__ out)
{
    __shared__ int h[NUM_REAL];
    const int img = blockIdx.y, ch = blockIdx.x, tid = threadIdx.x;
    if (img == 0) {                       // fold the two memset dispatches in here
        #pragma unroll
        for (int i = 0; i < (MP / NCHUNK); i += 256)
            if (i + tid < (MP / NCHUNK))
                negsum[ch * (MP / NCHUNK) + i + tid] = 0.f;
        if (ch == 0 && tid == 0) out[0] = 0.f;
    }
    if (tid < NUM_REAL) h[tid] = 0;
    __syncthreads();
    const int* lab = label + img * 1048576;
    const int p0 = ch * CHPIX + tid * 8;
    #pragma unroll
    for (int j = 0; j < 8; ++j) {
        int p = p0 + j;
        int c = lab[((p >> 8) << 12) + ((p & 255) << 2)];
        atomicAdd(&h[c], 1);
    }
    __syncthreads();
    if (tid < NUM_REAL) ghist[(img * NCHUNK + ch) * NUM_REAL + tid] = h[tid];
}

// ---------------- Kernel 1b: ordered scatter of first-131 pixels per class ----------------
// Early-exit: a block can only produce sel writes if some class has base < V_SEL
// (rank = base + in-chunk prefix >= base). For chunks past ~3 all 19 bases are
// >= V_SEL -> ~90% of blocks skip the label pass, LDS zero, and scan entirely.
__global__ __launch_bounds__(256) void k_scatter(const int* __restrict__ label,
                                                 const int* __restrict__ ghist,
                                                 int* __restrict__ sel)
{
    __shared__ int cnt[NUM_REAL * 256];
    __shared__ int base[NUM_REAL];
    const int img = blockIdx.y, ch = blockIdx.x, tid = threadIdx.x;
    if (tid < NUM_REAL) {
        int b = 0;
        for (int q = 0; q < ch; ++q) b += ghist[(img * NCHUNK + q) * NUM_REAL + tid];
        base[tid] = b;
    }
    __syncthreads();
    bool anyneed = false;
    #pragma unroll
    for (int k = 0; k < NUM_REAL; ++k) if (base[k] < V_SEL) anyneed = true;
    if (!anyneed) return;                 // block-uniform: no pixel here can rank < V_SEL
    #pragma unroll
    for (int k = 0; k < NUM_REAL; ++k) cnt[k * 256 + tid] = 0;   // own slots only
    const int* lab = label + img * 1048576;
    const int p0 = ch * CHPIX + tid * 8;
    #pragma unroll
    for (int j = 0; j < 8; ++j) {
        int p = p0 + j;
        int c = lab[((p >> 8) << 12) + ((p & 255) << 2)];
        cnt[c * 256 + tid]++;
    }
    __syncthreads();
    // wave-parallel exclusive scan: wave w owns classes w, w+4, ... (exact integer
    // equivalence with the old 1-thread-per-class serial scan)
    const int wave = tid >> 6, lane = tid & 63;
    for (int k = wave; k < NUM_REAL; k += 4) {
        const int bb = k * 256;
        int x0 = cnt[bb + lane],       x1 = cnt[bb + 64 + lane],
            x2 = cnt[bb + 128 + lane], x3 = cnt[bb + 192 + lane];
        const int v0 = x0, v1 = x1, v2 = x2, v3 = x3;
        #pragma unroll
        for (int d = 1; d < 64; d <<= 1) {
            int t0 = __shfl_up(x0, d, 64), t1 = __shfl_up(x1, d, 64);
            int t2 = __shfl_up(x2, d, 64), t3 = __shfl_up(x3, d, 64);
            if (lane >= d) { x0 += t0; x1 += t1; x2 += t2; x3 += t3; }
        }
        const int s0 = __shfl(x0, 63, 64);
        const int s1 = __shfl(x1, 63, 64);
        const int s2 = __shfl(x2, 63, 64);
        const int b0 = base[k];
        cnt[bb + lane]       = b0 + x0 - v0;
        cnt[bb + 64 + lane]  = b0 + s0 + x1 - v1;
        cnt[bb + 128 + lane] = b0 + s0 + s1 + x2 - v2;
        cnt[bb + 192 + lane] = b0 + s0 + s1 + s2 + x3 - v3;
    }
    __syncthreads();
    bool need = false;
    #pragma unroll
    for (int k = 0; k < NUM_REAL; ++k) if (cnt[k * 256 + tid] < V_SEL) need = true;
    if (need) {
        for (int j = 0; j < 8; ++j) {
            int p = p0 + j;
            int c = lab[((p >> 8) << 12) + ((p & 255) << 2)];
            int r = cnt[c * 256 + tid]++;
            if (r < V_SEL) sel[(img * NUM_REAL + c) * V_SEL + r] = p;
        }
    }
}

// ---------------- Kernel 2: fused gather + L2-normalize -> bf16 F[MP][256] ----------------
// one wave per output row: gather 256 channels, butterfly-reduce the norm,
// bf16 convert, in-wave LDS transpose, one ushort4 store per lane.
__global__ __launch_bounds__(256) void k_gather(const float* __restrict__ feats,
                                                const int* __restrict__ sel,
                                                unsigned short* __restrict__ F)
{
    __shared__ unsigned short rowbuf[4][256];
    const int tid = threadIdx.x, wave = tid >> 6, lane = tid & 63;
    const int r = blockIdx.x * 4 + wave;
    if (r < M_ROWS) {
        const int b = r / RPI;
        const int p = sel[r];
        const float* f0 = feats + (size_t)b * CDIM * P_PIX + p;
        float x0 = f0[(size_t)(lane      ) * P_PIX];
        float x1 = f0[(size_t)(lane + 64 ) * P_PIX];
        float x2 = f0[(size_t)(lane + 128) * P_PIX];
        float x3 = f0[(size_t)(lane + 192) * P_PIX];
        float ss = x0 * x0 + x1 * x1 + x2 * x2 + x3 * x3;
        #pragma unroll
        for (int d = 1; d < 64; d <<= 1) ss += __shfl_xor(ss, d, 64);
        const float rinv = 1.0f / fmaxf(sqrtf(ss), 1e-12f);
        __hip_bfloat16 h0 = __float2bfloat16(x0 * rinv);
        __hip_bfloat16 h1 = __float2bfloat16(x1 * rinv);
        __hip_bfloat16 h2 = __float2bfloat16(x2 * rinv);
        __hip_bfloat16 h3 = __float2bfloat16(x3 * rinv);
        rowbuf[wave][lane      ] = *reinterpret_cast<unsigned short*>(&h0);
        rowbuf[wave][lane + 64 ] = *reinterpret_cast<unsigned short*>(&h1);
        rowbuf[wave][lane + 128] = *reinterpret_cast<unsigned short*>(&h2);
        rowbuf[wave][lane + 192] = *reinterpret_cast<unsigned short*>(&h3);
        // same-wave LDS RAW: compiler inserts lgkmcnt wait; lanes are lockstep, no barrier
        ushort4 o = *reinterpret_cast<ushort4*>(&rowbuf[wave][lane * 4]);
        *reinterpret_cast<ushort4*>(F + (size_t)r * CDIM + lane * 4) = o;
    } else if (r < MP) {
        ushort4 z; z.x = z.y = z.z = z.w = 0;
        *reinterpret_cast<ushort4*>(F + (size_t)r * CDIM + lane * 4) = z;
    }
}

// ---------------- Kernel 3: symmetric Gram, fused different-class exp sums -> negsum ----------------
// T2 LDS chunk swizzle, full spread: physical 16B chunk (r,c) holds logical chunk
// c ^ f(r), f(r) = (r&3) ^ ((r>>2)&1). Staging pre-swizzles the GLOBAL source column
// (LDS dest stays linear, rule #21); reads use chunk qr^f(row). Per 16-lane read
// phase: 8 bank-slots x 2 lanes = the free 2-way aliasing floor.
__global__ __launch_bounds__(256) void k_gemm(const unsigned short* __restrict__ F,
                                              float* __restrict__ negsum)
{
    __shared__ unsigned short As[2][TILE * BK];
    __shared__ unsigned short Bs[2][TILE * BK];

    int t = blockIdx.x;                      // upper-triangular tile decode
    int bi = (int)((157.0f - sqrtf(24649.0f - 8.0f * (float)t)) * 0.5f);
    if (bi < 0) bi = 0;
    if (bi > 77) bi = 77;
    while ((bi + 1) * 78 - ((bi + 1) * bi) / 2 <= t) ++bi;
    while (bi * 78 - (bi * (bi - 1)) / 2 > t) --bi;
    int bj = bi + (t - (bi * 78 - (bi * (bi - 1)) / 2));
    const bool diag = (bi == bj);
    const int i0 = bi * TILE, j0 = bj * TILE;

    const int tid  = threadIdx.x;
    const int wave = tid >> 6, lane = tid & 63;
    const int qr = lane >> 4, lr = lane & 15;
    const int wr = (wave >> 1) * 64, wc = (wave & 1) * 64;

    floatx4 acc[4][4];
    floatx4 zero4 = {0.f, 0.f, 0.f, 0.f};
    #pragma unroll
    for (int a = 0; a < 4; ++a)
        #pragma unroll
        for (int b = 0; b < 4; ++b) acc[a][b] = zero4;

    const int srow = wave * 32 + (lane >> 2);
    // source logical chunk = (lane&3) ^ f(srow), f(srow) = ((lane>>2)&3) ^ ((lane>>4)&1)
    const int scol = ((lane & 3) ^ ((lane >> 2) & 3) ^ ((lane >> 4) & 1)) * 8;
    const unsigned short* gA = F + (size_t)(i0 + srow) * CDIM + scol;
    const unsigned short* gB = F + (size_t)(j0 + srow) * CDIM + scol;
    const int l0 = (wave * 32) * BK, l1 = (wave * 32 + 16) * BK;

    gld_lds16(gA,             &As[0][l0]);
    gld_lds16(gA + 16 * CDIM, &As[0][l1]);
    gld_lds16(gB,             &Bs[0][l0]);
    gld_lds16(gB + 16 * CDIM, &Bs[0][l1]);

    const int rchunk = (qr ^ (lr & 3) ^ ((lr >> 2) & 1)) * 8;  // swizzled read chunk

    #pragma unroll 2
    for (int k = 0; k < 8; ++k) {
        __syncthreads();                      // staging of buf[k&1] now visible
        const int cur = k & 1, nxt = cur ^ 1;
        if (k < 7) {                          // prefetch next chunk; drains at NEXT barrier
            const int kc = (k + 1) * BK;
            gld_lds16(gA + kc,             &As[nxt][l0]);
            gld_lds16(gA + kc + 16 * CDIM, &As[nxt][l1]);
            gld_lds16(gB + kc,             &Bs[nxt][l0]);
            gld_lds16(gB + kc + 16 * CDIM, &Bs[nxt][l1]);
        }
        short8 a[4], b[4];
        #pragma unroll
        for (int mi = 0; mi < 4; ++mi)
            a[mi] = *reinterpret_cast<const short8*>(&As[cur][(wr + mi * 16 + lr) * BK + rchunk]);
        #pragma unroll
        for (int ni = 0; ni < 4; ++ni)
            b[ni] = *reinterpret_cast<const short8*>(&Bs[cur][(wc + ni * 16 + lr) * BK + rchunk]);
        #pragma unroll
        for (int mi = 0; mi < 4; ++mi)
            #pragma unroll
            for (int ni = 0; ni < 4; ++ni)
                acc[mi][ni] = __builtin_amdgcn_mfma_f32_16x16x32_bf16(a[mi], b[ni], acc[mi][ni], 0, 0, 0);
    }

    // ---- epilogue: ns partial sums (different-class exp), LDS-staged, 256 atomics/tile ----
    int jcls[4];
    bool jval[4];
    #pragma unroll
    for (int ni = 0; ni < 4; ++ni) {
        int gcol = j0 + wc + ni * 16 + lr;
        jval[ni] = gcol < M_ROWS;
        unsigned tj = (unsigned)gcol / V_SEL;
        jcls[ni] = (int)(tj - (tj / NUM_REAL) * NUM_REAL);
    }
    float* red  = (float*)&As[0][0];   // [128][2] row partials (col-half per slot)
    float* cred = (float*)&Bs[0][0];   // [128][2] col partials (row-half per slot)
    float colacc[4] = {0.f, 0.f, 0.f, 0.f};
    #pragma unroll
    for (int mi = 0; mi < 4; ++mi) {
        #pragma unroll
        for (int reg = 0; reg < 4; ++reg) {
            int rloc = wr + mi * 16 + qr * 4 + reg;
            int grow = i0 + rloc;
            bool ival = grow < M_ROWS;
            unsigned ti = (unsigned)grow / V_SEL;
            int icls = (int)(ti - (ti / NUM_REAL) * NUM_REAL);
            float rowacc = 0.f;
            #pragma unroll
            for (int ni = 0; ni < 4; ++ni) {
                bool v = ival && jval[ni] && (icls != jcls[ni]);
                float e = v ? __expf(acc[mi][ni][reg] * 2.0f) : 0.f;
                rowacc += e;
                colacc[ni] += e;
            }
            rowacc += __shfl_xor(rowacc, 1, 64);
            rowacc += __shfl_xor(rowacc, 2, 64);
            rowacc += __shfl_xor(rowacc, 4, 64);
            rowacc += __shfl_xor(rowacc, 8, 64);
            if (lr == 0) red[rloc * 2 + (wave & 1)] = rowacc;
        }
    }
    #pragma unroll
    for (int ni = 0; ni < 4; ++ni) {
        float cc = colacc[ni];
        cc += __shfl_xor(cc, 16, 64);
        cc += __shfl_xor(cc, 32, 64);
        if (qr == 0) cred[(wc + ni * 16 + lr) * 2 + (wave >> 1)] = cc;
    }
    __syncthreads();
    if (tid < 128) {
        int row = i0 + tid;
        if (row < M_ROWS) atomicAdd(&negsum[row], red[tid * 2] + red[tid * 2 + 1]);
    } else {
        int cc2 = tid - 128, col = j0 + cc2;
        if (!diag && col < M_ROWS) atomicAdd(&negsum[col], cred[cc2 * 2] + cred[cc2 * 2 + 1]);
    }
}

// ---------------- Kernel 4: same-class Gram tiles -> positive loss terms ----------------
__global__ __launch_bounds__(256) void k_pos(const unsigned short* __restrict__ F,
                                             const float* __restrict__ negsum,
                                             float* __restrict__ out)
{
    __shared__ unsigned short As[2][TILE * BK];
    __shared__ unsigned short Bs[2][TILE * BK];
    __shared__ float wred[4];

    const int c = blockIdx.x / 15;
    int pidx = blockIdx.x % 15;
    int ti = 0;
    while (pidx >= CT - ti) { pidx -= CT - ti; ++ti; }
    const int tj = ti + pidx;
    const int u0i = ti * TILE, u0j = tj * TILE;
    const bool offd = (ti != tj);

    const int tid  = threadIdx.x;
    const int wave = tid >> 6, lane = tid & 63;
    const int qr = lane >> 4, lr = lane & 15;
    const int wr = (wave >> 1) * 64, wc = (wave & 1) * 64;

    floatx4 acc[4][4];
    floatx4 zero4 = {0.f, 0.f, 0.f, 0.f};
    #pragma unroll
    for (int a = 0; a < 4; ++a)
        #pragma unroll
        for (int b = 0; b < 4; ++b) acc[a][b] = zero4;

    const int srow = wave * 32 + (lane >> 2);
    const int scol = ((lane & 3) ^ ((lane >> 2) & 3) ^ ((lane >> 4) & 1)) * 8;
    auto growmap = [&](int u) -> int {
        int uc = u < 524 ? u : 523;
        int b = uc / 131, v = uc - 131 * b;
        return b * RPI + c * V_SEL + v;
    };
    const unsigned short* gA0 = F + (size_t)growmap(u0i + srow) * CDIM + scol;
    const unsigned short* gA1 = F + (size_t)growmap(u0i + srow + 16) * CDIM + scol;
    const unsigned short* gB0 = F + (size_t)growmap(u0j + srow) * CDIM + scol;
    const unsigned short* gB1 = F + (size_t)growmap(u0j + srow + 16) * CDIM + scol;
    const int l0 = (wave * 32) * BK, l1 = (wave * 32 + 16) * BK;

    gld_lds16(gA0, &As[0][l0]);
    gld_lds16(gA1, &As[0][l1]);
    gld_lds16(gB0, &Bs[0][l0]);
    gld_lds16(gB1, &Bs[0][l1]);

    const int rchunk = (qr ^ (lr & 3) ^ ((lr >> 2) & 1)) * 8;  // swizzled read chunk

    #pragma unroll 2
    for (int k = 0; k < 8; ++k) {
        __syncthreads();
        const int cur = k & 1, nxt = cur ^ 1;
        if (k < 7) {
            const int kc = (k + 1) * BK;
            gld_lds16(gA0 + kc, &As[nxt][l0]);
            gld_lds16(gA1 + kc, &As[nxt][l1]);
            gld_lds16(gB0 + kc, &Bs[nxt][l0]);
            gld_lds16(gB1 + kc, &Bs[nxt][l1]);
        }
        short8 a[4], b[4];
        #pragma unroll
        for (int mi = 0; mi < 4; ++mi)
            a[mi] = *reinterpret_cast<const short8*>(&As[cur][(wr + mi * 16 + lr) * BK + rchunk]);
        #pragma unroll
        for (int ni = 0; ni < 4; ++ni)
            b[ni] = *reinterpret_cast<const short8*>(&Bs[cur][(wc + ni * 16 + lr) * BK + rchunk]);
        #pragma unroll
        for (int mi = 0; mi < 4; ++mi)
            #pragma unroll
            for (int ni = 0; ni < 4; ++ni)
                acc[mi][ni] = __builtin_amdgcn_mfma_f32_16x16x32_bf16(a[mi], b[ni], acc[mi][ni], 0, 0, 0);
    }

    int  ujv[4];
    bool jval[4];
    float nsj[4];
    #pragma unroll
    for (int ni = 0; ni < 4; ++ni) {
        int uj = u0j + wc + ni * 16 + lr;
        ujv[ni] = uj;
        jval[ni] = uj < 524;
        nsj[ni] = jval[ni] ? negsum[growmap(uj)] : 0.f;
    }
    float tsum = 0.f;
    #pragma unroll
    for (int mi = 0; mi < 4; ++mi) {
        #pragma unroll
        for (int reg = 0; reg < 4; ++reg) {
            int ui = u0i + wr + mi * 16 + qr * 4 + reg;
            bool ival = ui < 524;
            float nsi = ival ? negsum[growmap(ui)] : 0.f;
            #pragma unroll
            for (int ni = 0; ni < 4; ++ni) {
                if (ival && jval[ni] && ui != ujv[ni]) {
                    float l  = acc[mi][ni][reg] * 2.0f;
                    float el = __expf(l);
                    tsum += l - __logf(el + nsi);
                    if (offd) tsum += l - __logf(el + nsj[ni]);
                }
            }
        }
    }
    #pragma unroll
    for (int s = 32; s > 0; s >>= 1) tsum += __shfl_xor(tsum, s, 64);
    if (lane == 0) wred[wave] = tsum;
    __syncthreads();
    if (tid == 0) {
        const float scale = -1.0f / (523.0f * (float)M_ROWS);
        atomicAdd(out, (wred[0] + wred[1] + wred[2] + wred[3]) * scale);
    }
}

extern "C" void kernel_launch(void* const* d_in, const int* in_sizes, int n_in,
                              void* d_out, int out_size, void* d_ws, size_t ws_size,
                              hipStream_t stream)
{
    const int*   label = (const int*)d_in[0];
    const float* feats = (const float*)d_in[1];
    float*       out   = (float*)d_out;

    char* ws = (char*)d_ws;
    unsigned short* F = (unsigned short*)ws;                    // MP*CDIM*2 = 5,111,808 B
    size_t off = (size_t)MP * CDIM * 2;
    int* sel = (int*)(ws + off);
    off += (size_t)T_TOT * V_SEL * 4;
    off = (off + 255) & ~(size_t)255;
    float* negsum = (float*)(ws + off);                         // MP floats
    off += (size_t)MP * 4;
    int* ghist = (int*)(ws + off);                              // 4*32*19 ints
    off += (size_t)NIMG * NCHUNK * NUM_REAL * 4;

    dim3 gh(NCHUNK, NIMG);
    k_hist<<<gh, 256, 0, stream>>>(label, ghist, negsum, out);
    k_scatter<<<gh, 256, 0, stream>>>(label, ghist, sel);
    k_gather<<<MP / 4, 256, 0, stream>>>(feats, sel, F);
    k_gemm<<<NT1, 256, 0, stream>>>(F, negsum);
    k_pos<<<NT2, 256, 0, stream>>>(F, negsum, out);
}

// Round 13
// 397.224 us; speedup vs baseline: 1.0123x; 1.0087x over previous
//
#include <hip/hip_runtime.h>
#include <hip/hip_bf16.h>

#define NUM_REAL 19
#define NIMG     4
#define T_TOT    76        // NIMG*NUM_REAL
#define V_SEL    131       // 10000 / 76
#define M_ROWS   9956      // T_TOT*V_SEL
#define MP       9984      // padded to 78*128
#define CDIM     256
#define P_PIX    65536
#define TILE     128
#define BK       32
#define RPI      2489      // rows per image = 19*131
#define NT1      3081      // 78*79/2 upper-triangular tiles
#define NCHUNK   32        // label chunks per image
#define CHPIX    2048      // dom pixels per chunk
#define CT       5         // 128-row tiles per 524-row class block
#define NT2      (NUM_REAL * 15)   // 19 classes * C(5+1,2) upper tiles

typedef __attribute__((ext_vector_type(8))) short short8;
typedef __attribute__((ext_vector_type(4))) float floatx4;

__device__ __forceinline__ void gld_lds16(const unsigned short* g, unsigned short* l) {
    // direct global->LDS, 16B per lane; LDS dest = wave-uniform base + lane*16
    __builtin_amdgcn_global_load_lds((__attribute__((address_space(1))) void*)(g),
                                     (__attribute__((address_space(3))) void*)(l),
                                     16, 0, 0);
}

// ---------------- Kernel 1a: per-chunk class histograms + workspace zeroing ----------------
__global__ __launch_bounds__(256) void k_hist(const int* __restrict__ label,
                                              int* __restrict__ ghist,
                                              float* __restrict__ negsum,
                                              float* __restrict__ out)
{
    __shared__ int h[NUM_REAL];
    const int img = blockIdx.y, ch = blockIdx.x, tid = threadIdx.x;
    if (img == 0) {                       // fold the two memset dispatches in here
        #pragma unroll
        for (int i = 0; i < (MP / NCHUNK); i += 256)
            if (i + tid < (MP / NCHUNK))
                negsum[ch * (MP / NCHUNK) + i + tid] = 0.f;
        if (ch == 0 && tid == 0) out[0] = 0.f;
    }
    if (tid < NUM_REAL) h[tid] = 0;
    __syncthreads();
    const int* lab = label + img * 1048576;
    const int p0 = ch * CHPIX + tid * 8;
    #pragma unroll
    for (int j = 0; j < 8; ++j) {
        int p = p0 + j;
        int c = lab[((p >> 8) << 12) + ((p & 255) << 2)];
        atomicAdd(&h[c], 1);
    }
    __syncthreads();
    if (tid < NUM_REAL) ghist[(img * NCHUNK + ch) * NUM_REAL + tid] = h[tid];
}

// ---------------- Kernel 1b: ordered scatter of first-131 pixels per class ----------------
// Early-exit: a block can only produce sel writes if some class has base < V_SEL.
__global__ __launch_bounds__(256) void k_scatter(const int* __restrict__ label,
                                                 const int* __restrict__ ghist,
                                                 int* __restrict__ sel)
{
    __shared__ int cnt[NUM_REAL * 256];
    __shared__ int base[NUM_REAL];
    const int img = blockIdx.y, ch = blockIdx.x, tid = threadIdx.x;
    if (tid < NUM_REAL) {
        int b = 0;
        for (int q = 0; q < ch; ++q) b += ghist[(img * NCHUNK + q) * NUM_REAL + tid];
        base[tid] = b;
    }
    __syncthreads();
    bool anyneed = false;
    #pragma unroll
    for (int k = 0; k < NUM_REAL; ++k) if (base[k] < V_SEL) anyneed = true;
    if (!anyneed) return;                 // block-uniform: no pixel here can rank < V_SEL
    #pragma unroll
    for (int k = 0; k < NUM_REAL; ++k) cnt[k * 256 + tid] = 0;   // own slots only
    const int* lab = label + img * 1048576;
    const int p0 = ch * CHPIX + tid * 8;
    #pragma unroll
    for (int j = 0; j < 8; ++j) {
        int p = p0 + j;
        int c = lab[((p >> 8) << 12) + ((p & 255) << 2)];
        cnt[c * 256 + tid]++;
    }
    __syncthreads();
    // wave-parallel exclusive scan: wave w owns classes w, w+4, ...
    const int wave = tid >> 6, lane = tid & 63;
    for (int k = wave; k < NUM_REAL; k += 4) {
        const int bb = k * 256;
        int x0 = cnt[bb + lane],       x1 = cnt[bb + 64 + lane],
            x2 = cnt[bb + 128 + lane], x3 = cnt[bb + 192 + lane];
        const int v0 = x0, v1 = x1, v2 = x2, v3 = x3;
        #pragma unroll
        for (int d = 1; d < 64; d <<= 1) {
            int t0 = __shfl_up(x0, d, 64), t1 = __shfl_up(x1, d, 64);
            int t2 = __shfl_up(x2, d, 64), t3 = __shfl_up(x3, d, 64);
            if (lane >= d) { x0 += t0; x1 += t1; x2 += t2; x3 += t3; }
        }
        const int s0 = __shfl(x0, 63, 64);
        const int s1 = __shfl(x1, 63, 64);
        const int s2 = __shfl(x2, 63, 64);
        const int b0 = base[k];
        cnt[bb + lane]       = b0 + x0 - v0;
        cnt[bb + 64 + lane]  = b0 + s0 + x1 - v1;
        cnt[bb + 128 + lane] = b0 + s0 + s1 + x2 - v2;
        cnt[bb + 192 + lane] = b0 + s0 + s1 + s2 + x3 - v3;
    }
    __syncthreads();
    bool need = false;
    #pragma unroll
    for (int k = 0; k < NUM_REAL; ++k) if (cnt[k * 256 + tid] < V_SEL) need = true;
    if (need) {
        for (int j = 0; j < 8; ++j) {
            int p = p0 + j;
            int c = lab[((p >> 8) << 12) + ((p & 255) << 2)];
            int r = cnt[c * 256 + tid]++;
            if (r < V_SEL) sel[(img * NUM_REAL + c) * V_SEL + r] = p;
        }
    }
}

// ---------------- Kernel 2: fused gather + L2-normalize -> bf16 F[MP][256] ----------------
__global__ __launch_bounds__(256) void k_gather(const float* __restrict__ feats,
                                                const int* __restrict__ sel,
                                                unsigned short* __restrict__ F)
{
    __shared__ unsigned short rowbuf[4][256];
    const int tid = threadIdx.x, wave = tid >> 6, lane = tid & 63;
    const int r = blockIdx.x * 4 + wave;
    if (r < M_ROWS) {
        const int b = r / RPI;
        const int p = sel[r];
        const float* f0 = feats + (size_t)b * CDIM * P_PIX + p;
        float x0 = f0[(size_t)(lane      ) * P_PIX];
        float x1 = f0[(size_t)(lane + 64 ) * P_PIX];
        float x2 = f0[(size_t)(lane + 128) * P_PIX];
        float x3 = f0[(size_t)(lane + 192) * P_PIX];
        float ss = x0 * x0 + x1 * x1 + x2 * x2 + x3 * x3;
        #pragma unroll
        for (int d = 1; d < 64; d <<= 1) ss += __shfl_xor(ss, d, 64);
        const float rinv = 1.0f / fmaxf(sqrtf(ss), 1e-12f);
        __hip_bfloat16 h0 = __float2bfloat16(x0 * rinv);
        __hip_bfloat16 h1 = __float2bfloat16(x1 * rinv);
        __hip_bfloat16 h2 = __float2bfloat16(x2 * rinv);
        __hip_bfloat16 h3 = __float2bfloat16(x3 * rinv);
        rowbuf[wave][lane      ] = *reinterpret_cast<unsigned short*>(&h0);
        rowbuf[wave][lane + 64 ] = *reinterpret_cast<unsigned short*>(&h1);
        rowbuf[wave][lane + 128] = *reinterpret_cast<unsigned short*>(&h2);
        rowbuf[wave][lane + 192] = *reinterpret_cast<unsigned short*>(&h3);
        // same-wave LDS RAW: compiler inserts lgkmcnt wait; lanes are lockstep, no barrier
        ushort4 o = *reinterpret_cast<ushort4*>(&rowbuf[wave][lane * 4]);
        *reinterpret_cast<ushort4*>(F + (size_t)r * CDIM + lane * 4) = o;
    } else if (r < MP) {
        ushort4 z; z.x = z.y = z.z = z.w = 0;
        *reinterpret_cast<ushort4*>(F + (size_t)r * CDIM + lane * 4) = z;
    }
}

// ---------------- Kernel 3: symmetric Gram, fused different-class exp sums -> negsum ----------------
// T2 LDS chunk swizzle (R6/R9, kept) + strip-major tile order with XCD chunking:
// strip I = tile-rows [8I,8I+8); within a strip walk columns bj, rows consecutive
// (column-major) -> 8 consecutive blocks share B(bj); ~128-block window = 8 A-panels
// + 16 B-panels ~ 1.5 MB < 4 MiB per-XCD L2. Bijective XCD chunking (3081=8*385+1)
// keeps each XCD's concurrent window contiguous in this order.
__global__ __launch_bounds__(256) void k_gemm(const unsigned short* __restrict__ F,
                                              float* __restrict__ negsum)
{
    __shared__ unsigned short As[2][TILE * BK];
    __shared__ unsigned short Bs[2][TILE * BK];

    // bijective XCD chunk remap (R3-verified): xcd 0 -> 386 slots, xcd 1..7 -> 385
    const int xcd = blockIdx.x & 7, pos = blockIdx.x >> 3;
    int s = (xcd < 1 ? 0 : 386 + (xcd - 1) * 385) + pos;

    // strip-major decode
    int I = 0, rI;
    for (;; ++I) {
        rI = (78 - 8 * I >= 8) ? 8 : (78 - 8 * I);
        int cnt = rI * (78 - 8 * I) - (rI * (rI - 1)) / 2;
        if (s < cnt) break;
        s -= cnt;
    }
    int bi, bj;
    const int triHead = (rI * (rI - 1)) / 2;
    if (s < triHead) {                    // triangular head: column j0 has j0+1 tiles
        int j0 = 0;
        while (s >= j0 + 1) { s -= j0 + 1; ++j0; }
        bi = 8 * I + s;
        bj = 8 * I + j0;
    } else {                              // full columns: col-major, rows consecutive
        s -= triHead;
        bi = 8 * I + s % rI;
        bj = 8 * I + (rI - 1) + s / rI;
    }
    const bool diag = (bi == bj);
    const int i0 = bi * TILE, j0c = bj * TILE;

    const int tid  = threadIdx.x;
    const int wave = tid >> 6, lane = tid & 63;
    const int qr = lane >> 4, lr = lane & 15;
    const int wr = (wave >> 1) * 64, wc = (wave & 1) * 64;

    floatx4 acc[4][4];
    floatx4 zero4 = {0.f, 0.f, 0.f, 0.f};
    #pragma unroll
    for (int a = 0; a < 4; ++a)
        #pragma unroll
        for (int b = 0; b < 4; ++b) acc[a][b] = zero4;

    const int srow = wave * 32 + (lane >> 2);
    // source logical chunk = (lane&3) ^ f(srow), f(srow) = ((lane>>2)&3) ^ ((lane>>4)&1)
    const int scol = ((lane & 3) ^ ((lane >> 2) & 3) ^ ((lane >> 4) & 1)) * 8;
    const unsigned short* gA = F + (size_t)(i0 + srow) * CDIM + scol;
    const unsigned short* gB = F + (size_t)(j0c + srow) * CDIM + scol;
    const int l0 = (wave * 32) * BK, l1 = (wave * 32 + 16) * BK;

    gld_lds16(gA,             &As[0][l0]);
    gld_lds16(gA + 16 * CDIM, &As[0][l1]);
    gld_lds16(gB,             &Bs[0][l0]);
    gld_lds16(gB + 16 * CDIM, &Bs[0][l1]);

    const int rchunk = (qr ^ (lr & 3) ^ ((lr >> 2) & 1)) * 8;  // swizzled read chunk

    #pragma unroll 2
    for (int k = 0; k < 8; ++k) {
        __syncthreads();                      // staging of buf[k&1] now visible
        const int cur = k & 1, nxt = cur ^ 1;
        if (k < 7) {                          // prefetch next chunk; drains at NEXT barrier
            const int kc = (k + 1) * BK;
            gld_lds16(gA + kc,             &As[nxt][l0]);
            gld_lds16(gA + kc + 16 * CDIM, &As[nxt][l1]);
            gld_lds16(gB + kc,             &Bs[nxt][l0]);
            gld_lds16(gB + kc + 16 * CDIM, &Bs[nxt][l1]);
        }
        short8 a[4], b[4];
        #pragma unroll
        for (int mi = 0; mi < 4; ++mi)
            a[mi] = *reinterpret_cast<const short8*>(&As[cur][(wr + mi * 16 + lr) * BK + rchunk]);
        #pragma unroll
        for (int ni = 0; ni < 4; ++ni)
            b[ni] = *reinterpret_cast<const short8*>(&Bs[cur][(wc + ni * 16 + lr) * BK + rchunk]);
        #pragma unroll
        for (int mi = 0; mi < 4; ++mi)
            #pragma unroll
            for (int ni = 0; ni < 4; ++ni)
                acc[mi][ni] = __builtin_amdgcn_mfma_f32_16x16x32_bf16(a[mi], b[ni], acc[mi][ni], 0, 0, 0);
    }

    // ---- epilogue: ns partial sums (different-class exp), LDS-staged, 256 atomics/tile ----
    int jcls[4];
    bool jval[4];
    #pragma unroll
    for (int ni = 0; ni < 4; ++ni) {
        int gcol = j0c + wc + ni * 16 + lr;
        jval[ni] = gcol < M_ROWS;
        unsigned tj = (unsigned)gcol / V_SEL;
        jcls[ni] = (int)(tj - (tj / NUM_REAL) * NUM_REAL);
    }
    float* red  = (float*)&As[0][0];   // [128][2] row partials (col-half per slot)
    float* cred = (float*)&Bs[0][0];   // [128][2] col partials (row-half per slot)
    float colacc[4] = {0.f, 0.f, 0.f, 0.f};
    #pragma unroll
    for (int mi = 0; mi < 4; ++mi) {
        #pragma unroll
        for (int reg = 0; reg < 4; ++reg) {
            int rloc = wr + mi * 16 + qr * 4 + reg;
            int grow = i0 + rloc;
            bool ival = grow < M_ROWS;
            unsigned ti = (unsigned)grow / V_SEL;
            int icls = (int)(ti - (ti / NUM_REAL) * NUM_REAL);
            float rowacc = 0.f;
            #pragma unroll
            for (int ni = 0; ni < 4; ++ni) {
                bool v = ival && jval[ni] && (icls != jcls[ni]);
                float e = v ? __expf(acc[mi][ni][reg] * 2.0f) : 0.f;
                rowacc += e;
                colacc[ni] += e;
            }
            rowacc += __shfl_xor(rowacc, 1, 64);
            rowacc += __shfl_xor(rowacc, 2, 64);
            rowacc += __shfl_xor(rowacc, 4, 64);
            rowacc += __shfl_xor(rowacc, 8, 64);
            if (lr == 0) red[rloc * 2 + (wave & 1)] = rowacc;
        }
    }
    #pragma unroll
    for (int ni = 0; ni < 4; ++ni) {
        float cc = colacc[ni];
        cc += __shfl_xor(cc, 16, 64);
        cc += __shfl_xor(cc, 32, 64);
        if (qr == 0) cred[(wc + ni * 16 + lr) * 2 + (wave >> 1)] = cc;
    }
    __syncthreads();
    if (tid < 128) {
        int row = i0 + tid;
        if (row < M_ROWS) atomicAdd(&negsum[row], red[tid * 2] + red[tid * 2 + 1]);
    } else {
        int cc2 = tid - 128, col = j0c + cc2;
        if (!diag && col < M_ROWS) atomicAdd(&negsum[col], cred[cc2 * 2] + cred[cc2 * 2 + 1]);
    }
}

// ---------------- Kernel 4: same-class Gram tiles -> positive loss terms ----------------
__global__ __launch_bounds__(256) void k_pos(const unsigned short* __restrict__ F,
                                             const float* __restrict__ negsum,
                                             float* __restrict__ out)
{
    __shared__ unsigned short As[2][TILE * BK];
    __shared__ unsigned short Bs[2][TILE * BK];
    __shared__ float wred[4];

    const int c = blockIdx.x / 15;
    int pidx = blockIdx.x % 15;
    int ti = 0;
    while (pidx >= CT - ti) { pidx -= CT - ti; ++ti; }
    const int tj = ti + pidx;
    const int u0i = ti * TILE, u0j = tj * TILE;
    const bool offd = (ti != tj);

    const int tid  = threadIdx.x;
    const int wave = tid >> 6, lane = tid & 63;
    const int qr = lane >> 4, lr = lane & 15;
    const int wr = (wave >> 1) * 64, wc = (wave & 1) * 64;

    floatx4 acc[4][4];
    floatx4 zero4 = {0.f, 0.f, 0.f, 0.f};
    #pragma unroll
    for (int a = 0; a < 4; ++a)
        #pragma unroll
        for (int b = 0; b < 4; ++b) acc[a][b] = zero4;

    const int srow = wave * 32 + (lane >> 2);
    const int scol = ((lane & 3) ^ ((lane >> 2) & 3) ^ ((lane >> 4) & 1)) * 8;
    auto growmap = [&](int u) -> int {
        int uc = u < 524 ? u : 523;
        int b = uc / 131, v = uc - 131 * b;
        return b * RPI + c * V_SEL + v;
    };
    const unsigned short* gA0 = F + (size_t)growmap(u0i + srow) * CDIM + scol;
    const unsigned short* gA1 = F + (size_t)growmap(u0i + srow + 16) * CDIM + scol;
    const unsigned short* gB0 = F + (size_t)growmap(u0j + srow) * CDIM + scol;
    const unsigned short* gB1 = F + (size_t)growmap(u0j + srow + 16) * CDIM + scol;
    const int l0 = (wave * 32) * BK, l1 = (wave * 32 + 16) * BK;

    gld_lds16(gA0, &As[0][l0]);
    gld_lds16(gA1, &As[0][l1]);
    gld_lds16(gB0, &Bs[0][l0]);
    gld_lds16(gB1, &Bs[0][l1]);

    const int rchunk = (qr ^ (lr & 3) ^ ((lr >> 2) & 1)) * 8;  // swizzled read chunk

    #pragma unroll 2
    for (int k = 0; k < 8; ++k) {
        __syncthreads();
        const int cur = k & 1, nxt = cur ^ 1;
        if (k < 7) {
            const int kc = (k + 1) * BK;
            gld_lds16(gA0 + kc, &As[nxt][l0]);
            gld_lds16(gA1 + kc, &As[nxt][l1]);
            gld_lds16(gB0 + kc, &Bs[nxt][l0]);
            gld_lds16(gB1 + kc, &Bs[nxt][l1]);
        }
        short8 a[4], b[4];
        #pragma unroll
        for (int mi = 0; mi < 4; ++mi)
            a[mi] = *reinterpret_cast<const short8*>(&As[cur][(wr + mi * 16 + lr) * BK + rchunk]);
        #pragma unroll
        for (int ni = 0; ni < 4; ++ni)
            b[ni] = *reinterpret_cast<const short8*>(&Bs[cur][(wc + ni * 16 + lr) * BK + rchunk]);
        #pragma unroll
        for (int mi = 0; mi < 4; ++mi)
            #pragma unroll
            for (int ni = 0; ni < 4; ++ni)
                acc[mi][ni] = __builtin_amdgcn_mfma_f32_16x16x32_bf16(a[mi], b[ni], acc[mi][ni], 0, 0, 0);
    }

    int  ujv[4];
    bool jval[4];
    float nsj[4];
    #pragma unroll
    for (int ni = 0; ni < 4; ++ni) {
        int uj = u0j + wc + ni * 16 + lr;
        ujv[ni] = uj;
        jval[ni] = uj < 524;
        nsj[ni] = jval[ni] ? negsum[growmap(uj)] : 0.f;
    }
    float tsum = 0.f;
    #pragma unroll
    for (int mi = 0; mi < 4; ++mi) {
        #pragma unroll
        for (int reg = 0; reg < 4; ++reg) {
            int ui = u0i + wr + mi * 16 + qr * 4 + reg;
            bool ival = ui < 524;
            float nsi = ival ? negsum[growmap(ui)] : 0.f;
            #pragma unroll
            for (int ni = 0; ni < 4; ++ni) {
                if (ival && jval[ni] && ui != ujv[ni]) {
                    float l  = acc[mi][ni][reg] * 2.0f;
                    float el = __expf(l);
                    tsum += l - __logf(el + nsi);
                    if (offd) tsum += l - __logf(el + nsj[ni]);
                }
            }
        }
    }
    #pragma unroll
    for (int sft = 32; sft > 0; sft >>= 1) tsum += __shfl_xor(tsum, sft, 64);
    if (lane == 0) wred[wave] = tsum;
    __syncthreads();
    if (tid == 0) {
        const float scale = -1.0f / (523.0f * (float)M_ROWS);
        atomicAdd(out, (wred[0] + wred[1] + wred[2] + wred[3]) * scale);
    }
}

extern "C" void kernel_launch(void* const* d_in, const int* in_sizes, int n_in,
                              void* d_out, int out_size, void* d_ws, size_t ws_size,
                              hipStream_t stream)
{
    const int*   label = (const int*)d_in[0];
    const float* feats = (const float*)d_in[1];
    float*       out   = (float*)d_out;

    char* ws = (char*)d_ws;
    unsigned short* F = (unsigned short*)ws;                    // MP*CDIM*2 = 5,111,808 B
    size_t off = (size_t)MP * CDIM * 2;
    int* sel = (int*)(ws + off);
    off += (size_t)T_TOT * V_SEL * 4;
    off = (off + 255) & ~(size_t)255;
    float* negsum = (float*)(ws + off);                         // MP floats
    off += (size_t)MP * 4;
    int* ghist = (int*)(ws + off);                              // 4*32*19 ints
    off += (size_t)NIMG * NCHUNK * NUM_REAL * 4;

    dim3 gh(NCHUNK, NIMG);
    k_hist<<<gh, 256, 0, stream>>>(label, ghist, negsum, out);
    k_scatter<<<gh, 256, 0, stream>>>(label, ghist, sel);
    k_gather<<<MP / 4, 256, 0, stream>>>(feats, sel, F);
    k_gemm<<<NT1, 256, 0, stream>>>(F, negsum);
    k_pos<<<NT2, 256, 0, stream>>>(F, negsum, out);
}